// Round 4
// baseline (119.270 us; speedup 1.0000x reference)
//
#include <hip/hip_runtime.h>
#include <math.h>

typedef _Float16 f16;
typedef __attribute__((ext_vector_type(8))) _Float16 f16x8;
typedef __attribute__((ext_vector_type(16))) float f32x16;

// sat (128,4,64,16) f32, grd (128,4,64,16) f32
// out (f32): sat 524288 | grd 524288 | distance[g][s] 16384 | orien[s][g] 16384
#define DIST_OFF  1048576
#define ORI_OFF   1064960
#define SATP_STR  72      // f16 elems per satP row (144 B = 36 dwords -> conflict-free)

#define MFMA(a,b,c) __builtin_amdgcn_mfma_f32_32x32x16_f16((a),(b),(c),0,0,0)

// Convert 8 consecutive f32 into f16 hi + lo fragments (bit-identical to prep path).
__device__ inline void cvt8(float4 a, float4 b, f16x8* hi, f16x8* lo) {
    float va[8] = {a.x, a.y, a.z, a.w, b.x, b.y, b.z, b.w};
    f16x8 h, l;
    #pragma unroll
    for (int e = 0; e < 8; ++e) {
        f16 hv = (f16)va[e];
        h[e] = hv;
        l[e] = (f16)(va[e] - (float)hv);
    }
    *hi = h; *lo = l;
}

// ---- fused kernel: block=(s, g-quarter32), 8 waves = (j-tile 2) x (k-quarter 4) ----
// Each wave owns ONE 32x32 output tile for a 1024-wide K-quarter:
//   acc = 2 x f32x16 (32 VGPR) instead of 8 (128 VGPR)  -> 4 waves/SIMD
//   LDS = satP 36.6 KB (exchange buffers alias it)      -> 2 blocks/CU
__global__ __launch_bounds__(512, 4) void corr_k(const float* __restrict__ sat,
                                                 const float* __restrict__ grd,
                                                 float* __restrict__ out,
                                                 const float4* __restrict__ satIn,
                                                 const float4* __restrict__ grdIn,
                                                 float4* __restrict__ out4) {
    __shared__ __align__(16) unsigned char smem[36864];  // satP; aliased post-loop
    __shared__ float wred[8];
    __shared__ float rnormS;
    f16* sH = (f16*)smem;                 // [w' 0..126][hc 0..63], stride 72
    f16* sL = sH + 127 * SATP_STR;
    float* pPart = (float*)smem;          // [jt 2][kq-1 3][j0 32][m 32] = 6144 f
    float* corrF = (float*)smem + 6144;   // [j 64][g 32] = 2048 f

    const int tid = threadIdx.x;
    const int s  = blockIdx.x >> 2;
    const int gq = blockIdx.x & 3;
    const int wave = tid >> 6, lane = tid & 63;
    const int m = lane & 31, half = lane >> 5;
    const int jt = wave & 1, kq = wave >> 1;

    // ---- stage satP hi/lo (doubled along w) + ||sat[s]||^2 (round-0 exact order) ----
    const float* satS = sat + s * 4096;
    float ssq = 0.f;
    #pragma unroll
    for (int r = 0; r < 8; ++r) {
        int idx = r * 512 + tid;
        float v = satS[idx];
        int h = idx >> 10, w = (idx >> 4) & 63, c = idx & 15;
        int col = h * 16 + c;
        f16 hv = (f16)v, lv = (f16)(v - (float)hv);
        sH[w * SATP_STR + col] = hv;
        sL[w * SATP_STR + col] = lv;
        if (w < 63) { sH[(w + 64) * SATP_STR + col] = hv; sL[(w + 64) * SATP_STR + col] = lv; }
        ssq += v * v;
    }
    #pragma unroll
    for (int off = 32; off > 0; off >>= 1) ssq += __shfl_down(ssq, off, 64);
    if (lane == 0) wred[wave] = ssq;
    __syncthreads();
    if (tid == 0) {
        float t = 0.f;
        #pragma unroll
        for (int i = 0; i < 8; ++i) t += wred[i];
        rnormS = 1.f / fmaxf(sqrtf(t), 1e-12f);
    }

    // ---- K-loop: 64 k-tiles of 16; double-buffered; cvt deferred to consume-time ----
    // A rows: j = jt*32 + m (+ w-shift via ao);  B: 8 contiguous floats in raw grd.
    const f16* A0h = sH + (jt * 32 + m) * SATP_STR + half * 8;
    const f16* A0l = sL + (jt * 32 + m) * SATP_STR + half * 8;
    const float* Bg = grd + (gq * 32 + m) * 4096 + half * 8;

    f32x16 hA, xA;
    #pragma unroll
    for (int r = 0; r < 16; ++r) { hA[r] = 0.f; xA[r] = 0.f; }

    f16x8 ah[2], al[2], bh, bl;
    float4 br[2][2];

#define LOADA(p, t) { int ao = ((t) >> 2) * SATP_STR + ((t) & 3) * 16; \
    ah[p] = *(const f16x8*)(A0h + ao); al[p] = *(const f16x8*)(A0l + ao); }
#define LOADB(p, t) { int fo = ((t) & 3) * 1024 + ((t) >> 2) * 16; \
    br[p][0] = *(const float4*)(Bg + fo); br[p][1] = *(const float4*)(Bg + fo + 4); }

    const int tb = kq * 64, tmax = tb + 63;
    LOADA(0, tb) LOADB(0, tb)
    #pragma unroll 4
    for (int tt = 0; tt < 64; ++tt) {
        int tn = (tt < 63) ? tb + tt + 1 : tmax;     // last extra load lands in dead buffer
        LOADA((tt + 1) & 1, tn)
        LOADB((tt + 1) & 1, tn)
        cvt8(br[tt & 1][0], br[tt & 1][1], &bh, &bl);   // waits on loads from PREV iter
        hA = MFMA(ah[tt & 1], bh, hA);
        xA = MFMA(ah[tt & 1], bl, xA);
        xA = MFMA(al[tt & 1], bh, xA);
    }
    f32x16 p = hA + xA;

    __syncthreads();                       // satP dead everywhere; safe to alias

    // ---- cross-wave K-quarter reduce: ascending-kq left-assoc sum ----
    if (kq != 0) {
        float* dst = pPart + (jt * 3 + (kq - 1)) * 1024;
        #pragma unroll
        for (int r = 0; r < 16; ++r) {
            int j0 = (r & 3) + 8 * (r >> 2) + 4 * half;
            dst[j0 * 32 + m] = p[r];
        }
    }
    __syncthreads();
    if (kq == 0) {
        const float* q1 = pPart + (jt * 3 + 0) * 1024;
        const float* q2 = pPart + (jt * 3 + 1) * 1024;
        const float* q3 = pPart + (jt * 3 + 2) * 1024;
        #pragma unroll
        for (int r = 0; r < 16; ++r) {
            int j0 = (r & 3) + 8 * (r >> 2) + 4 * half;
            int a = j0 * 32 + m;
            float v = ((p[r] + q1[a]) + q2[a]) + q3[a];
            corrF[(jt * 32 + j0) * 32 + m] = v;
        }
    }
    __syncthreads();

    // ---- argmax over j (serial, exact first-occurrence), distance + orien ----
    if (tid < 32) {
        int g = tid;
        float best = corrF[g];
        int bj = 0;
        for (int j = 1; j < 64; ++j) {
            float v = corrF[j * 32 + g];
            if (v > best) { best = v; bj = j; }
        }
        float dot = best * rnormS;
        int gg = gq * 32 + g;
        out[DIST_OFF + gg * 128 + s] = 2.f - 2.f * dot;
        out[ORI_OFF + s * 128 + gg]  = (float)bj;
    }

    // ---- fused passthrough copies (512 blocks x 512 thr = 262144 float4) ----
    {
        int i = blockIdx.x * 512 + tid;
        out4[i] = (i < 131072) ? satIn[i] : grdIn[i - 131072];
    }
}

extern "C" void kernel_launch(void* const* d_in, const int* in_sizes, int n_in,
                              void* d_out, int out_size, void* d_ws, size_t ws_size,
                              hipStream_t stream) {
    const float* sat = (const float*)d_in[0];
    const float* grd = (const float*)d_in[1];
    float* out = (float*)d_out;
    // Single dispatch; d_ws unused (its 42us poison fill is unconditional - R2).
    corr_k<<<512, 512, 0, stream>>>(sat, grd, out,
                                    (const float4*)sat, (const float4*)grd, (float4*)out);
}

// Round 5
// 86.884 us; speedup vs baseline: 1.3728x; 1.3728x over previous
//
#include <hip/hip_runtime.h>
#include <math.h>

typedef _Float16 f16;
typedef __attribute__((ext_vector_type(8))) _Float16 f16x8;
typedef __attribute__((ext_vector_type(16))) float f32x16;

// sat (128,4,64,16) f32, grd (128,4,64,16) f32
// out (f32): sat 524288 | grd 524288 | distance[g][s] 16384 | orien[s][g] 16384
#define DIST_OFF  1048576
#define ORI_OFF   1064960
#define SATP_STR  72      // f16 elems per satP row (144 B = 36 dwords)

#define MFMA(a,b,c) __builtin_amdgcn_mfma_f32_32x32x16_f16((a),(b),(c),0,0,0)

// ---- prep: grd -> frag-ready grdF[kb][g] hi/lo f16x8 (k = w*64 + h*16 + c) ----
// Proven round-0 kernel (absmax 0.0). 64 blocks.
__global__ __launch_bounds__(256) void prep_k(const float* __restrict__ grd,
                                              f16* __restrict__ gHi, f16* __restrict__ gLo) {
    const int b = blockIdx.x;
    __shared__ f16 tH[8192], tL[8192];          // [kb_l 64][g_l 16][e 8]
    const int tid = threadIdx.x;
    const int g0 = (b & 7) * 16;
    const int kq = b >> 3;                      // k-range [kq*512, kq*512+512)
    #pragma unroll
    for (int i = 0; i < 32; ++i) {
        int flat = i * 256 + tid;               // [g_l 16][h 4][j 128], coalesced reads
        int g_l = flat >> 9;
        int r   = flat & 511;
        int h   = r >> 7;
        int j   = r & 127;                      // dw_l = j>>4, c = j&15
        float v = grd[(((g0 + g_l) * 4 + h) * 64 + kq * 8) * 16 + j];
        int k_l = (j >> 4) * 64 + h * 16 + (j & 15);
        f16 hv = (f16)v;
        int a = (k_l >> 3) * 128 + g_l * 8 + (k_l & 7);
        tH[a] = hv;
        tL[a] = (f16)(v - (float)hv);
    }
    __syncthreads();
    #pragma unroll
    for (int i = 0; i < 4; ++i) {
        int f = i * 256 + tid;                  // frag: kb_l = f>>4, g_l = f&15
        int dst = (kq * 64 + (f >> 4)) * 128 + g0 + (f & 15);
        ((f16x8*)gHi)[dst] = *(const f16x8*)(tH + f * 8);
        ((f16x8*)gLo)[dst] = *(const f16x8*)(tL + f * 8);
    }
}

// ---- corr: block=(s, g-quarter32), 8 waves = 8-way K split, wave tile 64j x 32g ----
// acc = 4 x f32x16 (64 VGPR) -> ~110 total -> 4 waves/SIMD; LDS 64KB -> 2 blocks/CU.
// Inner loop: pure f16x8 loads + 6 MFMA per k-tile (NO conversion - prep'd B).
__global__ __launch_bounds__(512, 4) void corr_k(const float* __restrict__ sat,
                                                 const f16* __restrict__ gHi,
                                                 const f16* __restrict__ gLo,
                                                 float* __restrict__ out,
                                                 const float4* __restrict__ satIn,
                                                 const float4* __restrict__ grdIn,
                                                 float4* __restrict__ out4,
                                                 int doCopy) {
    __shared__ __align__(16) unsigned char smem[65536];  // satP 36.6KB; red[8][64][32] aliases
    __shared__ float wred[8];
    __shared__ float rnormS;
    f16* sH = (f16*)smem;                 // [w' 0..126][hc 0..63], stride 72
    f16* sL = sH + 127 * SATP_STR;
    float* red = (float*)smem;            // [kq 8][j 64][g 32] = 16384 f = 64KB

    const int tid = threadIdx.x;
    const int s  = blockIdx.x >> 2;
    const int gq = blockIdx.x & 3;
    const int wave = tid >> 6, lane = tid & 63;
    const int m = lane & 31, half = lane >> 5;

    // ---- stage satP hi/lo (doubled along w) + ||sat[s]||^2 (round-0 exact order) ----
    const float* satS = sat + s * 4096;
    float ssq = 0.f;
    #pragma unroll
    for (int r = 0; r < 8; ++r) {
        int idx = r * 512 + tid;
        float v = satS[idx];
        int h = idx >> 10, w = (idx >> 4) & 63, c = idx & 15;
        int col = h * 16 + c;
        f16 hv = (f16)v, lv = (f16)(v - (float)hv);
        sH[w * SATP_STR + col] = hv;
        sL[w * SATP_STR + col] = lv;
        if (w < 63) { sH[(w + 64) * SATP_STR + col] = hv; sL[(w + 64) * SATP_STR + col] = lv; }
        ssq += v * v;
    }
    #pragma unroll
    for (int off = 32; off > 0; off >>= 1) ssq += __shfl_down(ssq, off, 64);
    if (lane == 0) wred[wave] = ssq;
    __syncthreads();
    if (tid == 0) {
        float t = 0.f;
        #pragma unroll
        for (int i = 0; i < 8; ++i) t += wred[i];
        rnormS = 1.f / fmaxf(sqrtf(t), 1e-12f);
    }

    // ---- K-loop: kq = wave, 32 k-tiles of 16; B double-buffered from L2 ----
    const f16* A0h = sH + m * SATP_STR + half * 8;
    const f16* A0l = sL + m * SATP_STR + half * 8;
    const f16x8* BHp = (const f16x8*)gHi;
    const f16x8* BLp = (const f16x8*)gLo;
    const int bBase = half * 128 + gq * 32 + m;      // frag idx = t*256 + bBase

    f32x16 z;
    #pragma unroll
    for (int r = 0; r < 16; ++r) z[r] = 0.f;
    f32x16 h0 = z, h1 = z, x0 = z, x1 = z;

    f16x8 a0h, a0l, a1h, a1l, bh[2], bl[2];

#define LOADB(p, t) { int bu = (t) * 256 + bBase; bh[p] = BHp[bu]; bl[p] = BLp[bu]; }
#define LOADA(t) { int ao = ((t) >> 2) * SATP_STR + ((t) & 3) * 16; \
    a0h = *(const f16x8*)(A0h + ao); a0l = *(const f16x8*)(A0l + ao); \
    a1h = *(const f16x8*)(A0h + ao + 32 * SATP_STR); \
    a1l = *(const f16x8*)(A0l + ao + 32 * SATP_STR); }

    const int t0 = wave * 32;
    LOADB(0, t0)
    #pragma unroll
    for (int tt = 0; tt < 32; ++tt) {
        if (tt < 31) LOADB((tt + 1) & 1, t0 + tt + 1)   // static parity (full unroll)
        LOADA(t0 + tt)
        h0 = MFMA(a0h, bh[tt & 1], h0);
        h1 = MFMA(a1h, bh[tt & 1], h1);
        x0 = MFMA(a0h, bl[tt & 1], x0); x0 = MFMA(a0l, bh[tt & 1], x0);
        x1 = MFMA(a1h, bl[tt & 1], x1); x1 = MFMA(a1l, bh[tt & 1], x1);
    }
    f32x16 p0 = h0 + x0, p1 = h1 + x1;

    // ---- 8-way K-partial reduce in LDS (satP dead; red aliases it) ----
    __syncthreads();
    float* rw = red + wave * 2048;
    #pragma unroll
    for (int r = 0; r < 16; ++r) {
        int j0 = (r & 3) + 8 * (r >> 2) + 4 * half;      // j within 32-tile
        rw[j0 * 32 + m]        = p0[r];
        rw[(j0 + 32) * 32 + m] = p1[r];
    }
    __syncthreads();
    #pragma unroll
    for (int i = 0; i < 4; ++i) {
        int c = i * 512 + tid;                           // j = c>>5, g = c&31
        float v = red[c]          + red[c + 2048]  + red[c + 4096]  + red[c + 6144]
                + red[c + 8192]   + red[c + 10240] + red[c + 12288] + red[c + 14336];
        red[c] = v;                                      // own-cell only: race-free
    }
    __syncthreads();

    // ---- argmax over j (serial, exact first-occurrence), distance + orien ----
    if (tid < 32) {
        int g = tid;
        float best = red[g];
        int bj = 0;
        for (int j = 1; j < 64; ++j) {
            float v = red[j * 32 + g];
            if (v > best) { best = v; bj = j; }
        }
        float dot = best * rnormS;
        int gg = gq * 32 + g;
        out[DIST_OFF + gg * 128 + s] = 2.f - 2.f * dot;
        out[ORI_OFF + s * 128 + gg]  = (float)bj;
    }

    // ---- fused passthrough copies (512 blocks x 512 thr = 262144 float4) ----
    if (doCopy) {
        int i = blockIdx.x * 512 + tid;
        out4[i] = (i < 131072) ? satIn[i] : grdIn[i - 131072];
    }
}

// Fallback passthrough copies (when grdF was staged inside d_out's sat region)
__global__ void copy_k(const float4* __restrict__ a, const float4* __restrict__ b,
                       float4* __restrict__ out) {
    int i = blockIdx.x * 256 + threadIdx.x;
    out[i] = a[i];
    out[131072 + i] = b[i];
}

extern "C" void kernel_launch(void* const* d_in, const int* in_sizes, int n_in,
                              void* d_out, int out_size, void* d_ws, size_t ws_size,
                              hipStream_t stream) {
    const float* sat = (const float*)d_in[0];
    const float* grd = (const float*)d_in[1];
    float* out = (float*)d_out;

    // ws poison fill is unconditional (proven R2), so using d_ws costs nothing.
    const bool useWs = (ws_size >= (size_t)2 * 1024 * 1024);
    f16* gHi;
    f16* gLo;
    if (useWs) {
        gHi = (f16*)d_ws;
        gLo = gHi + 524288;
    } else {
        gHi = (f16*)out;                 // floats [0, 262144)
        gLo = (f16*)(out + 262144);      // floats [262144, 524288)
    }

    prep_k<<<64, 256, 0, stream>>>(grd, gHi, gLo);
    corr_k<<<512, 512, 0, stream>>>(sat, gHi, gLo, out,
                                    (const float4*)sat, (const float4*)grd, (float4*)out,
                                    useWs ? 1 : 0);
    if (!useWs)
        copy_k<<<512, 256, 0, stream>>>((const float4*)sat, (const float4*)grd, (float4*)out);
}